// Round 2
// baseline (267.804 us; speedup 1.0000x reference)
//
#include <hip/hip_runtime.h>
#include <cstdint>
#include <cmath>

#define IN_FEATURES 1024
#define OUT_FEATURES 1024
#define NUM_GMM 5
#define ROWS ((IN_FEATURES + 1) * OUT_FEATURES)   // 1049600

struct U2 { uint32_t a, b; };

__host__ __device__ constexpr uint32_t rotl32c(uint32_t x, int d) {
  return (x << d) | (x >> (32 - d));
}

// Exact JAX threefry2x32 (20 rounds, 5 key injections) — jax/_src/prng.py
#define TF_ROUND(r) { x0 += x1; x1 = rotl32c(x1, (r)); x1 ^= x0; }
__host__ __device__ constexpr U2 threefry2x32(uint32_t k0, uint32_t k1,
                                              uint32_t x0, uint32_t x1) {
  const uint32_t ks0 = k0, ks1 = k1, ks2 = k0 ^ k1 ^ 0x1BD11BDAu;
  x0 += ks0; x1 += ks1;
  TF_ROUND(13) TF_ROUND(15) TF_ROUND(26) TF_ROUND(6)
  x0 += ks1; x1 += ks2 + 1u;
  TF_ROUND(17) TF_ROUND(29) TF_ROUND(16) TF_ROUND(24)
  x0 += ks2; x1 += ks0 + 2u;
  TF_ROUND(13) TF_ROUND(15) TF_ROUND(26) TF_ROUND(6)
  x0 += ks0; x1 += ks1 + 3u;
  TF_ROUND(17) TF_ROUND(29) TF_ROUND(16) TF_ROUND(24)
  x0 += ks1; x1 += ks2 + 4u;
  TF_ROUND(13) TF_ROUND(15) TF_ROUND(26) TF_ROUND(6)
  x0 += ks2; x1 += ks0 + 5u;
  return U2{x0, x1};
}

// jax_threefry_partitionable=True (default since JAX 0.5.0):
//   split(key, (2,)) fold-like: subkey i = (y0, y1) of threefry(key, hi32(i)=0, lo32(i)=i)
//   random_bits(shape, 32): element flat-index j -> (y0 ^ y1) of threefry(key, 0, j)
constexpr U2 KC = threefry2x32(0u, 42u, 0u, 0u);   // kcat
constexpr U2 KN = threefry2x32(0u, 42u, 0u, 1u);   // knorm
constexpr uint32_t KCAT0  = KC.a;
constexpr uint32_t KCAT1  = KC.b;
constexpr uint32_t KNORM0 = KN.a;
constexpr uint32_t KNORM1 = KN.b;

__device__ inline float u01_from_bits(uint32_t bits) {
  // XLA: bitcast((bits>>9)|0x3F800000) - 1.0f  -> [0, 1)
  return __uint_as_float((bits >> 9) | 0x3F800000u) - 1.0f;
}

__device__ inline float gumbel_from_bits(uint32_t bits) {
  // uniform(minval=tiny, maxval=1): (1-tiny)==1.0f in fp32; f+tiny==f unless f==0
  float f = u01_from_bits(bits);
  float u = fmaxf(1.17549435e-38f, f + 1.17549435e-38f);
  // -log(-log(u)), each log rounded to f32 (chained correctly-rounded f32 logs)
  float t1 = (float)log((double)u);
  float t2 = (float)log((double)(-t1));
  return -t2;
}

// XLA's ErfInv f32 expansion (Giles polynomial, xla math.cc)
__device__ inline float erfinv_xla(float x) {
  float w = -log1pf(-x * x);
  float p;
  if (w < 5.0f) {
    w = w - 2.5f;
    p = 2.81022636e-08f;
    p = fmaf(p, w, 3.43273939e-07f);
    p = fmaf(p, w, -3.5233877e-06f);
    p = fmaf(p, w, -4.39150654e-06f);
    p = fmaf(p, w, 0.00021858087f);
    p = fmaf(p, w, -0.00125372503f);
    p = fmaf(p, w, -0.00417768164f);
    p = fmaf(p, w, 0.246640727f);
    p = fmaf(p, w, 1.50140941f);
  } else {
    w = sqrtf(w) - 3.0f;
    p = -0.000200214257f;
    p = fmaf(p, w, 0.000100950558f);
    p = fmaf(p, w, 0.00134934322f);
    p = fmaf(p, w, -0.00367342844f);
    p = fmaf(p, w, 0.00573950773f);
    p = fmaf(p, w, -0.0076224613f);
    p = fmaf(p, w, 0.00943887047f);
    p = fmaf(p, w, 1.00167406f);
    p = fmaf(p, w, 2.83297682f);
  }
  return p * x;
}

__device__ inline float normal_from_bits(uint32_t bits) {
  float f = u01_from_bits(bits);
  const float lo = -0.99999994f;          // nextafter(-1, 0) in f32
  float u = fmaxf(lo, f * 2.0f + lo);     // (hi-lo) rounds to exactly 2.0f
  return 1.4142135623730951f * erfinv_xla(u);
}

// One thread per row r: 5 gumbel draws (counter r*5+g) + 1 normal draw (counter r)
__global__ __launch_bounds__(256) void gmm_sample_kernel(
    const float* __restrict__ mean, const float* __restrict__ logstd,
    const float* __restrict__ weight, float* __restrict__ wb) {
  int r = blockIdx.x * blockDim.x + threadIdx.x;
  if (r >= ROWS) return;

  const float* wrow = weight + (size_t)r * NUM_GMM;
  int idx = 0;
  float best = -3.402823466e+38f;
#pragma unroll
  for (int g = 0; g < NUM_GMM; ++g) {
    U2 t = threefry2x32(KCAT0, KCAT1, 0u, (uint32_t)(r * NUM_GMM + g));
    float v = gumbel_from_bits(t.a ^ t.b) + wrow[g];
    if (v > best) { best = v; idx = g; }   // strict >: first-max wins (jnp.argmax)
  }

  U2 tn = threefry2x32(KNORM0, KNORM1, 0u, (uint32_t)r);
  float eps = normal_from_bits(tn.a ^ tn.b);

  float m = mean[(size_t)r * NUM_GMM + idx];
  float l = logstd[(size_t)r * NUM_GMM + idx];
  float sd = (float)exp(tanh((double)l) * 3.0);
  wb[r] = m + sd * eps;
}

// out[M,1024] = x[M,1024] @ W^T + bias, W = wb+1024 (row-major N x K), bias = wb[0:1024]
#define BM 64
#define BN 64
#define BK 16
#define LDT (BM + 4)   // +4 keeps float4 alignment of LDS rows, breaks bank stride

__global__ __launch_bounds__(256) void gemm_bias_kernel(
    const float* __restrict__ x, const float* __restrict__ wb,
    float* __restrict__ out) {
  __shared__ float As[BK][LDT];
  __shared__ float Bs[BK][LDT];
  const float* W = wb + OUT_FEATURES;
  const int bn = blockIdx.x * BN;
  const int bm = blockIdx.y * BM;
  const int tid = threadIdx.x;
  const int lrow = tid >> 2;          // 0..63
  const int lk = (tid & 3) << 2;      // 0,4,8,12
  const int tx = tid & 15;            // n-dim micro-tile
  const int ty = tid >> 4;            // m-dim micro-tile

  const float* xg = x + (size_t)(bm + lrow) * IN_FEATURES + lk;
  const float* wg = W + (size_t)(bn + lrow) * IN_FEATURES + lk;

  float acc[4][4] = {{0.f}};
  for (int k0 = 0; k0 < IN_FEATURES; k0 += BK) {
    float4 a = *(const float4*)(xg + k0);
    float4 b = *(const float4*)(wg + k0);
    As[lk + 0][lrow] = a.x; As[lk + 1][lrow] = a.y;
    As[lk + 2][lrow] = a.z; As[lk + 3][lrow] = a.w;
    Bs[lk + 0][lrow] = b.x; Bs[lk + 1][lrow] = b.y;
    Bs[lk + 2][lrow] = b.z; Bs[lk + 3][lrow] = b.w;
    __syncthreads();
#pragma unroll
    for (int k = 0; k < BK; ++k) {
      const float4 av = *(const float4*)&As[k][ty * 4];
      const float4 bv = *(const float4*)&Bs[k][tx * 4];
      const float a4[4] = {av.x, av.y, av.z, av.w};
      const float b4[4] = {bv.x, bv.y, bv.z, bv.w};
#pragma unroll
      for (int i = 0; i < 4; ++i)
#pragma unroll
        for (int j = 0; j < 4; ++j)
          acc[i][j] = fmaf(a4[i], b4[j], acc[i][j]);
    }
    __syncthreads();
  }

  const float4 bias = *(const float4*)(wb + bn + tx * 4);
#pragma unroll
  for (int i = 0; i < 4; ++i) {
    float4 o;
    o.x = acc[i][0] + bias.x;
    o.y = acc[i][1] + bias.y;
    o.z = acc[i][2] + bias.z;
    o.w = acc[i][3] + bias.w;
    *(float4*)(out + (size_t)(bm + ty * 4 + i) * OUT_FEATURES + bn + tx * 4) = o;
  }
}

extern "C" void kernel_launch(void* const* d_in, const int* in_sizes, int n_in,
                              void* d_out, int out_size, void* d_ws, size_t ws_size,
                              hipStream_t stream) {
  const float* x      = (const float*)d_in[0];
  const float* mean   = (const float*)d_in[1];
  const float* logstd = (const float*)d_in[2];
  const float* weight = (const float*)d_in[3];
  float* out = (float*)d_out;
  float* wb  = (float*)d_ws;   // ROWS floats = 4.2 MB scratch

  const int M = in_sizes[0] / IN_FEATURES;   // 4096

  // Stage 1: sample weight_bias (RNG-exact vs JAX partitionable threefry)
  gmm_sample_kernel<<<(ROWS + 255) / 256, 256, 0, stream>>>(
      mean, logstd, weight, wb);

  // Stage 2: out = x @ W^T + bias
  dim3 grid(OUT_FEATURES / BN, M / BM);
  gemm_bias_kernel<<<grid, 256, 0, stream>>>(x, wb, out);
}

// Round 3
// 151.283 us; speedup vs baseline: 1.7702x; 1.7702x over previous
//
#include <hip/hip_runtime.h>
#include <cstdint>
#include <cmath>

#define IN_FEATURES 1024
#define OUT_FEATURES 1024
#define NUM_GMM 5
#define ROWS ((IN_FEATURES + 1) * OUT_FEATURES)   // 1049600

struct U2 { uint32_t a, b; };

__host__ __device__ constexpr uint32_t rotl32c(uint32_t x, int d) {
  return (x << d) | (x >> (32 - d));
}

// Exact JAX threefry2x32 (20 rounds, 5 key injections) — jax/_src/prng.py
#define TF_ROUND(r) { x0 += x1; x1 = rotl32c(x1, (r)); x1 ^= x0; }
__host__ __device__ constexpr U2 threefry2x32(uint32_t k0, uint32_t k1,
                                              uint32_t x0, uint32_t x1) {
  const uint32_t ks0 = k0, ks1 = k1, ks2 = k0 ^ k1 ^ 0x1BD11BDAu;
  x0 += ks0; x1 += ks1;
  TF_ROUND(13) TF_ROUND(15) TF_ROUND(26) TF_ROUND(6)
  x0 += ks1; x1 += ks2 + 1u;
  TF_ROUND(17) TF_ROUND(29) TF_ROUND(16) TF_ROUND(24)
  x0 += ks2; x1 += ks0 + 2u;
  TF_ROUND(13) TF_ROUND(15) TF_ROUND(26) TF_ROUND(6)
  x0 += ks0; x1 += ks1 + 3u;
  TF_ROUND(17) TF_ROUND(29) TF_ROUND(16) TF_ROUND(24)
  x0 += ks1; x1 += ks2 + 4u;
  TF_ROUND(13) TF_ROUND(15) TF_ROUND(26) TF_ROUND(6)
  x0 += ks2; x1 += ks0 + 5u;
  return U2{x0, x1};
}

// jax_threefry_partitionable=True (verified Round 2):
//   split: subkey i = both words of threefry(key, 0, i)
//   random_bits: element j -> y0 ^ y1 of threefry(key, 0, j)
constexpr U2 KC = threefry2x32(0u, 42u, 0u, 0u);   // kcat
constexpr U2 KN = threefry2x32(0u, 42u, 0u, 1u);   // knorm
constexpr uint32_t KCAT0  = KC.a;
constexpr uint32_t KCAT1  = KC.b;
constexpr uint32_t KNORM0 = KN.a;
constexpr uint32_t KNORM1 = KN.b;

__device__ inline float u01_from_bits(uint32_t bits) {
  return __uint_as_float((bits >> 9) | 0x3F800000u) - 1.0f;
}

// Compact f64 log, err ~1e-13 rel -> f32 result correctly rounded (no libm).
// Valid for normal positive x (our inputs: u in [2^-126, 1), v in [5.9e-8, 88.8]).
__device__ inline float log_f32_acc(float x) {
  uint32_t ix = __float_as_uint(x);
  int e = (int)(ix >> 23) - 127;
  float mf = __uint_as_float((ix & 0x007FFFFFu) | 0x3F800000u); // [1,2)
  if (mf > 1.4142135381698608f) { mf *= 0.5f; e += 1; }         // (0.707,1.414]
  double m = (double)mf;
  double t = (m - 1.0) / (m + 1.0);   // |t| <= 0.1716
  double t2 = t * t;
  double p = 1.0 / 15.0;
  p = fma(p, t2, 1.0 / 13.0);
  p = fma(p, t2, 1.0 / 11.0);
  p = fma(p, t2, 1.0 / 9.0);
  p = fma(p, t2, 1.0 / 7.0);
  p = fma(p, t2, 1.0 / 5.0);
  p = fma(p, t2, 1.0 / 3.0);
  p = fma(p, t2, 1.0);
  double r = fma((double)e, 0.693147180559945309417, 2.0 * t * p);
  return (float)r;
}

__device__ inline float gumbel_from_bits(uint32_t bits) {
  float f = u01_from_bits(bits);
  float u = fmaxf(1.17549435e-38f, f + 1.17549435e-38f);
  float t1 = log_f32_acc(u);          // f32-rounded, matches ref's CR logf
  float t2 = log_f32_acc(-t1);
  return -t2;
}

// XLA ErfInv f32 (Giles) — smooth, f32 chain matches ref within ulps
__device__ inline float erfinv_xla(float x) {
  float w = -log1pf(-x * x);
  float p;
  if (w < 5.0f) {
    w = w - 2.5f;
    p = 2.81022636e-08f;
    p = fmaf(p, w, 3.43273939e-07f);
    p = fmaf(p, w, -3.5233877e-06f);
    p = fmaf(p, w, -4.39150654e-06f);
    p = fmaf(p, w, 0.00021858087f);
    p = fmaf(p, w, -0.00125372503f);
    p = fmaf(p, w, -0.00417768164f);
    p = fmaf(p, w, 0.246640727f);
    p = fmaf(p, w, 1.50140941f);
  } else {
    w = sqrtf(w) - 3.0f;
    p = -0.000200214257f;
    p = fmaf(p, w, 0.000100950558f);
    p = fmaf(p, w, 0.00134934322f);
    p = fmaf(p, w, -0.00367342844f);
    p = fmaf(p, w, 0.00573950773f);
    p = fmaf(p, w, -0.0076224613f);
    p = fmaf(p, w, 0.00943887047f);
    p = fmaf(p, w, 1.00167406f);
    p = fmaf(p, w, 2.83297682f);
  }
  return p * x;
}

__device__ inline float normal_from_bits(uint32_t bits) {
  float f = u01_from_bits(bits);
  const float lo = -0.99999994f;
  float u = fmaxf(lo, f * 2.0f + lo);
  return 1.4142135623730951f * erfinv_xla(u);
}

__device__ inline unsigned short f32_to_bf16_rne(float f) {
  uint32_t u = __float_as_uint(f);
  return (unsigned short)((u + 0x7FFFu + ((u >> 16) & 1u)) >> 16);
}

__global__ __launch_bounds__(256) void gmm_sample_kernel(
    const float* __restrict__ mean, const float* __restrict__ logstd,
    const float* __restrict__ weight, unsigned short* __restrict__ wh,
    float* __restrict__ bias_f32) {
  int r = blockIdx.x * blockDim.x + threadIdx.x;
  if (r >= ROWS) return;

  const float* wrow = weight + (size_t)r * NUM_GMM;
  int idx = 0;
  float best = -3.402823466e+38f;
#pragma unroll
  for (int g = 0; g < NUM_GMM; ++g) {
    U2 t = threefry2x32(KCAT0, KCAT1, 0u, (uint32_t)(r * NUM_GMM + g));
    float v = gumbel_from_bits(t.a ^ t.b) + wrow[g];
    if (v > best) { best = v; idx = g; }   // strict >: first-max (jnp.argmax)
  }

  U2 tn = threefry2x32(KNORM0, KNORM1, 0u, (uint32_t)r);
  float eps = normal_from_bits(tn.a ^ tn.b);

  float m = mean[(size_t)r * NUM_GMM + idx];
  float l = logstd[(size_t)r * NUM_GMM + idx];
  float sd = expf(tanhf(l) * 3.0f);       // smooth path: f32 ok
  float wbv = m + sd * eps;
  wh[r] = f32_to_bf16_rne(wbv);
  if (r < OUT_FEATURES) bias_f32[r] = wbv;
}

__global__ __launch_bounds__(256) void convert_x_kernel(
    const float* __restrict__ x, unsigned short* __restrict__ xh) {
  int i = (blockIdx.x * 256 + threadIdx.x) * 8;
  float4 a = *(const float4*)(x + i);
  float4 b = *(const float4*)(x + i + 4);
  union { unsigned short s[8]; uint4 v; } o;
  o.s[0] = f32_to_bf16_rne(a.x); o.s[1] = f32_to_bf16_rne(a.y);
  o.s[2] = f32_to_bf16_rne(a.z); o.s[3] = f32_to_bf16_rne(a.w);
  o.s[4] = f32_to_bf16_rne(b.x); o.s[5] = f32_to_bf16_rne(b.y);
  o.s[6] = f32_to_bf16_rne(b.z); o.s[7] = f32_to_bf16_rne(b.w);
  *(uint4*)(xh + i) = o.v;
}

// ---------------- MFMA GEMM: out[M,1024] = xh @ W'^T + bias ----------------
typedef __attribute__((ext_vector_type(8))) short bf16x8;
typedef __attribute__((ext_vector_type(4))) float f32x4;

#define GBM 128
#define GBN 64
#define GBK 32

__device__ inline void load_lds16(const void* g, void* l) {
  __builtin_amdgcn_global_load_lds(
      (const __attribute__((address_space(1))) unsigned int*)g,
      (__attribute__((address_space(3))) unsigned int*)l, 16, 0, 0);
}

// LDS layout: slot s (16B) = [block b(=row>>4)][h(=kchunk)][m(=row&15)],
// s = (b*4+h)*16+m. Staging thread t -> slot t (lane-linear, satisfies
// global_load_lds wave-uniform+lane*16). Fragment read for 16x16x32 MFMA:
// lane L needs row(L&15), k=8*(L>>4).. = slot b*64 + L -> ds_read_b128 at
// base + 16L: conflict-free.
__global__ __launch_bounds__(256) void gemm_mfma_kernel(
    const unsigned short* __restrict__ xh, const unsigned short* __restrict__ wh,
    const float* __restrict__ bias, float* __restrict__ out) {
  __shared__ unsigned short As[GBM * GBK];   // 8192 B
  __shared__ unsigned short Bs[GBN * GBK];   // 4096 B

  const unsigned short* W = wh + OUT_FEATURES;
  const int tid = threadIdx.x;
  const int w = tid >> 6;
  const int L = tid & 63;

  const int m_tile = blockIdx.y * GBM;
  const int n_tile = blockIdx.x * GBN;

  const int sm = tid & 15;          // row within 16-block
  const int sh = (tid >> 4) & 3;    // k-chunk (8 elems)
  const int sb = tid >> 6;          // block index 0..3

  const unsigned short* gA0 = xh + (size_t)(m_tile + sb * 16 + sm) * IN_FEATURES + 8 * sh;
  const unsigned short* gA1 = xh + (size_t)(m_tile + (sb + 4) * 16 + sm) * IN_FEATURES + 8 * sh;
  const unsigned short* gB  = W  + (size_t)(n_tile + sb * 16 + sm) * IN_FEATURES + 8 * sh;

  f32x4 acc[4][2];
#pragma unroll
  for (int f = 0; f < 4; ++f)
#pragma unroll
    for (int j = 0; j < 2; ++j) acc[f][j] = (f32x4){0.f, 0.f, 0.f, 0.f};

  const int aoff = (w >> 1) * 4 * 512 + L * 8;   // ushort index; 512 = block stride
  const int boff = (w & 1) * 2 * 512 + L * 8;

  for (int k0 = 0; k0 < IN_FEATURES; k0 += GBK) {
    load_lds16(gA0 + k0, As + (size_t)tid * 8);
    load_lds16(gA1 + k0, As + (size_t)(256 + tid) * 8);
    load_lds16(gB + k0,  Bs + (size_t)tid * 8);
    __syncthreads();

    bf16x8 a0 = *(const bf16x8*)(As + aoff);
    bf16x8 a1 = *(const bf16x8*)(As + aoff + 512);
    bf16x8 a2 = *(const bf16x8*)(As + aoff + 1024);
    bf16x8 a3 = *(const bf16x8*)(As + aoff + 1536);
    bf16x8 b0 = *(const bf16x8*)(Bs + boff);
    bf16x8 b1 = *(const bf16x8*)(Bs + boff + 512);

    acc[0][0] = __builtin_amdgcn_mfma_f32_16x16x32_bf16(a0, b0, acc[0][0], 0, 0, 0);
    acc[0][1] = __builtin_amdgcn_mfma_f32_16x16x32_bf16(a0, b1, acc[0][1], 0, 0, 0);
    acc[1][0] = __builtin_amdgcn_mfma_f32_16x16x32_bf16(a1, b0, acc[1][0], 0, 0, 0);
    acc[1][1] = __builtin_amdgcn_mfma_f32_16x16x32_bf16(a1, b1, acc[1][1], 0, 0, 0);
    acc[2][0] = __builtin_amdgcn_mfma_f32_16x16x32_bf16(a2, b0, acc[2][0], 0, 0, 0);
    acc[2][1] = __builtin_amdgcn_mfma_f32_16x16x32_bf16(a2, b1, acc[2][1], 0, 0, 0);
    acc[3][0] = __builtin_amdgcn_mfma_f32_16x16x32_bf16(a3, b0, acc[3][0], 0, 0, 0);
    acc[3][1] = __builtin_amdgcn_mfma_f32_16x16x32_bf16(a3, b1, acc[3][1], 0, 0, 0);
    __syncthreads();
  }

  // Epilogue: C/D layout col = L&15, row = (L>>4)*4 + reg (m89-verified)
  const int col_base = n_tile + (w & 1) * 32 + (L & 15);
  const int row_base = m_tile + (w >> 1) * 64 + (L >> 4) * 4;
  float bv0 = bias[col_base];
  float bv1 = bias[col_base + 16];
#pragma unroll
  for (int f = 0; f < 4; ++f) {
#pragma unroll
    for (int reg = 0; reg < 4; ++reg) {
      int row = row_base + f * 16 + reg;
      out[(size_t)row * OUT_FEATURES + col_base]      = acc[f][0][reg] + bv0;
      out[(size_t)row * OUT_FEATURES + col_base + 16] = acc[f][1][reg] + bv1;
    }
  }
}

extern "C" void kernel_launch(void* const* d_in, const int* in_sizes, int n_in,
                              void* d_out, int out_size, void* d_ws, size_t ws_size,
                              hipStream_t stream) {
  const float* x      = (const float*)d_in[0];
  const float* mean   = (const float*)d_in[1];
  const float* logstd = (const float*)d_in[2];
  const float* weight = (const float*)d_in[3];
  float* out = (float*)d_out;

  const int M = in_sizes[0] / IN_FEATURES;   // 4096

  // ws layout: xh bf16 [M*1024] | wh bf16 [ROWS] | bias f32 [1024]
  unsigned short* xh = (unsigned short*)d_ws;
  unsigned short* wh = (unsigned short*)((char*)d_ws + (size_t)M * IN_FEATURES * 2);
  float* biasf = (float*)((char*)wh + (size_t)ROWS * 2);

  gmm_sample_kernel<<<(ROWS + 255) / 256, 256, 0, stream>>>(
      mean, logstd, weight, wh, biasf);

  convert_x_kernel<<<(M * IN_FEATURES) / (256 * 8), 256, 0, stream>>>(x, xh);

  dim3 grid(OUT_FEATURES / GBN, M / GBM);
  gemm_mfma_kernel<<<grid, 256, 0, stream>>>(xh, wh, biasf, out);
}

// Round 4
// 144.949 us; speedup vs baseline: 1.8476x; 1.0437x over previous
//
#include <hip/hip_runtime.h>
#include <cstdint>
#include <cmath>

#define IN_FEATURES 1024
#define OUT_FEATURES 1024
#define NUM_GMM 5
#define ROWS ((IN_FEATURES + 1) * OUT_FEATURES)   // 1049600 = 4100*256

struct U2 { uint32_t a, b; };

__host__ __device__ constexpr uint32_t rotl32c(uint32_t x, int d) {
  return (x << d) | (x >> (32 - d));
}

// Exact JAX threefry2x32 (20 rounds, 5 key injections)
#define TF_ROUND(r) { x0 += x1; x1 = rotl32c(x1, (r)); x1 ^= x0; }
__host__ __device__ constexpr U2 threefry2x32(uint32_t k0, uint32_t k1,
                                              uint32_t x0, uint32_t x1) {
  const uint32_t ks0 = k0, ks1 = k1, ks2 = k0 ^ k1 ^ 0x1BD11BDAu;
  x0 += ks0; x1 += ks1;
  TF_ROUND(13) TF_ROUND(15) TF_ROUND(26) TF_ROUND(6)
  x0 += ks1; x1 += ks2 + 1u;
  TF_ROUND(17) TF_ROUND(29) TF_ROUND(16) TF_ROUND(24)
  x0 += ks2; x1 += ks0 + 2u;
  TF_ROUND(13) TF_ROUND(15) TF_ROUND(26) TF_ROUND(6)
  x0 += ks0; x1 += ks1 + 3u;
  TF_ROUND(17) TF_ROUND(29) TF_ROUND(16) TF_ROUND(24)
  x0 += ks1; x1 += ks2 + 4u;
  TF_ROUND(13) TF_ROUND(15) TF_ROUND(26) TF_ROUND(6)
  x0 += ks2; x1 += ks0 + 5u;
  return U2{x0, x1};
}

// jax_threefry_partitionable=True (verified R2)
constexpr U2 KC = threefry2x32(0u, 42u, 0u, 0u);   // kcat
constexpr U2 KN = threefry2x32(0u, 42u, 0u, 1u);   // knorm
constexpr uint32_t KCAT0  = KC.a;
constexpr uint32_t KCAT1  = KC.b;
constexpr uint32_t KNORM0 = KN.a;
constexpr uint32_t KNORM1 = KN.b;

__device__ inline float u01_from_bits(uint32_t bits) {
  return __uint_as_float((bits >> 9) | 0x3F800000u) - 1.0f;
}

// f64-lite log: rcp_f32 seed + 2 Newton steps replaces IEEE f64 divide.
// Total err ~1e-16 rel -> f32 result correctly rounded (argmax-safe).
__device__ inline float log_f32_acc(float x) {
  uint32_t ix = __float_as_uint(x);
  int e = (int)(ix >> 23) - 127;
  float mf = __uint_as_float((ix & 0x007FFFFFu) | 0x3F800000u); // [1,2)
  if (mf > 1.4142135381698608f) { mf *= 0.5f; e += 1; }         // (0.707,1.414]
  double m = (double)mf;
  double d = m + 1.0;                               // [1.707, 2.414]
  double r = (double)__builtin_amdgcn_rcpf((float)d);
  r = r * (2.0 - d * r);                            // Newton 1: ~1e-12
  r = r * (2.0 - d * r);                            // Newton 2: ~1e-16
  double t = (m - 1.0) * r;                         // |t| <= 0.1716
  double t2 = t * t;
  double p = 1.0 / 15.0;
  p = fma(p, t2, 1.0 / 13.0);
  p = fma(p, t2, 1.0 / 11.0);
  p = fma(p, t2, 1.0 / 9.0);
  p = fma(p, t2, 1.0 / 7.0);
  p = fma(p, t2, 1.0 / 5.0);
  p = fma(p, t2, 1.0 / 3.0);
  p = fma(p, t2, 1.0);
  double res = fma((double)e, 0.693147180559945309417, 2.0 * t * p);
  return (float)res;
}

__device__ inline float gumbel_from_bits(uint32_t bits) {
  float f = u01_from_bits(bits);
  float u = fmaxf(1.17549435e-38f, f + 1.17549435e-38f);
  float t1 = log_f32_acc(u);
  float t2 = log_f32_acc(-t1);
  return -t2;
}

// XLA ErfInv f32 (Giles) — smooth path
__device__ inline float erfinv_xla(float x) {
  float w = -log1pf(-x * x);
  float p;
  if (w < 5.0f) {
    w = w - 2.5f;
    p = 2.81022636e-08f;
    p = fmaf(p, w, 3.43273939e-07f);
    p = fmaf(p, w, -3.5233877e-06f);
    p = fmaf(p, w, -4.39150654e-06f);
    p = fmaf(p, w, 0.00021858087f);
    p = fmaf(p, w, -0.00125372503f);
    p = fmaf(p, w, -0.00417768164f);
    p = fmaf(p, w, 0.246640727f);
    p = fmaf(p, w, 1.50140941f);
  } else {
    w = sqrtf(w) - 3.0f;
    p = -0.000200214257f;
    p = fmaf(p, w, 0.000100950558f);
    p = fmaf(p, w, 0.00134934322f);
    p = fmaf(p, w, -0.00367342844f);
    p = fmaf(p, w, 0.00573950773f);
    p = fmaf(p, w, -0.0076224613f);
    p = fmaf(p, w, 0.00943887047f);
    p = fmaf(p, w, 1.00167406f);
    p = fmaf(p, w, 2.83297682f);
  }
  return p * x;
}

__device__ inline float normal_from_bits(uint32_t bits) {
  float f = u01_from_bits(bits);
  const float lo = -0.99999994f;
  float u = fmaxf(lo, f * 2.0f + lo);
  return 1.4142135623730951f * erfinv_xla(u);
}

__device__ inline unsigned short f32_to_bf16_rne(float f) {
  uint32_t u = __float_as_uint(f);
  return (unsigned short)((u + 0x7FFFu + ((u >> 16) & 1u)) >> 16);
}

// Fused: sample weight_bias row r (all threads) + convert 8 x floats (first
// 524288 threads). Memory-bound convert overlaps VALU-bound sampling.
__global__ __launch_bounds__(256) void prep_kernel(
    const float* __restrict__ mean, const float* __restrict__ logstd,
    const float* __restrict__ weight, const float* __restrict__ x,
    unsigned short* __restrict__ wh, float* __restrict__ bias_f32,
    unsigned short* __restrict__ xh, int n_chunks) {
  const int r = blockIdx.x * 256 + threadIdx.x;   // grid covers ROWS exactly

  // ---- x conversion (independent work, overlaps) ----
  if (r < n_chunks) {
    int i = r * 8;
    float4 a = *(const float4*)(x + i);
    float4 b = *(const float4*)(x + i + 4);
    union { unsigned short s[8]; uint4 v; } o;
    o.s[0] = f32_to_bf16_rne(a.x); o.s[1] = f32_to_bf16_rne(a.y);
    o.s[2] = f32_to_bf16_rne(a.z); o.s[3] = f32_to_bf16_rne(a.w);
    o.s[4] = f32_to_bf16_rne(b.x); o.s[5] = f32_to_bf16_rne(b.y);
    o.s[6] = f32_to_bf16_rne(b.z); o.s[7] = f32_to_bf16_rne(b.w);
    *(uint4*)(xh + i) = o.v;
  }

  // ---- GMM sampling ----
  const float* wrow = weight + (size_t)r * NUM_GMM;
  int idx = 0;
  float best = -3.402823466e+38f;
#pragma unroll
  for (int g = 0; g < NUM_GMM; ++g) {
    U2 t = threefry2x32(KCAT0, KCAT1, 0u, (uint32_t)(r * NUM_GMM + g));
    float v = gumbel_from_bits(t.a ^ t.b) + wrow[g];
    if (v > best) { best = v; idx = g; }   // strict >: first-max (jnp.argmax)
  }

  U2 tn = threefry2x32(KNORM0, KNORM1, 0u, (uint32_t)r);
  float eps = normal_from_bits(tn.a ^ tn.b);

  float m = mean[(size_t)r * NUM_GMM + idx];
  float l = logstd[(size_t)r * NUM_GMM + idx];
  // fast tanh/exp: sd = exp(3*tanh(l)); rel err ~1e-6 (negligible vs bf16)
  float e2 = __expf(2.0f * l);
  float th = 1.0f - 2.0f * __builtin_amdgcn_rcpf(e2 + 1.0f);
  float sd = __expf(3.0f * th);
  float wbv = m + sd * eps;
  wh[r] = f32_to_bf16_rne(wbv);
  if (r < OUT_FEATURES) bias_f32[r] = wbv;
}

// ---------------- MFMA GEMM: out[M,1024] = xh @ W'^T + bias ----------------
typedef __attribute__((ext_vector_type(8))) short bf16x8;
typedef __attribute__((ext_vector_type(4))) float f32x4;

#define GBM 128
#define GBN 64
#define GBK 64

__device__ inline void load_lds16(const void* g, void* l) {
  __builtin_amdgcn_global_load_lds(
      (const __attribute__((address_space(1))) unsigned int*)g,
      (__attribute__((address_space(3))) unsigned int*)l, 16, 0, 0);
}

// LDS slot layout (16B slots): slot = ((blk*2 + ksub)*4 + kchunk)*16 + mrow.
// Staging thread t -> slots t, t+256, ... (lane-linear: wave base + lane*16).
// Fragment read for 16x16x32 MFMA: lane L -> slot (blk*2+ksub)*64 + L, i.e.
// ds_read_b128 at base + 16*L: conflict-free (m97 pattern).
__global__ __launch_bounds__(256) void gemm_mfma_kernel(
    const unsigned short* __restrict__ xh, const unsigned short* __restrict__ wh,
    const float* __restrict__ bias, float* __restrict__ out) {
  __shared__ unsigned short As[2][GBM * GBK];   // 2 x 16 KB
  __shared__ unsigned short Bs[2][GBN * GBK];   // 2 x 8 KB

  const unsigned short* W = wh + OUT_FEATURES;
  const int tid = threadIdx.x;
  const int w = tid >> 6;
  const int L = tid & 63;

  const int m_tile = blockIdx.y * GBM;
  const int n_tile = blockIdx.x * GBN;

  // staging decomposition of slot index t
  const int sm = tid & 15;           // row within 16-block
  const int sh = (tid >> 4) & 3;     // k-chunk (8 elems)
  const int sk = (tid >> 6) & 1;     // k-subtile (0/1)
  const int sb = tid >> 7;           // block base (0/1)
  const int kofs = sk * 32 + sh * 8;

  const unsigned short* gA[4];
  const unsigned short* gB[2];
#pragma unroll
  for (int i = 0; i < 4; ++i)
    gA[i] = xh + (size_t)(m_tile + (2 * i + sb) * 16 + sm) * IN_FEATURES + kofs;
#pragma unroll
  for (int i = 0; i < 2; ++i)
    gB[i] = W + (size_t)(n_tile + (2 * i + sb) * 16 + sm) * IN_FEATURES + kofs;

  f32x4 acc[2][4];
#pragma unroll
  for (int a = 0; a < 2; ++a)
#pragma unroll
    for (int b = 0; b < 4; ++b) acc[a][b] = (f32x4){0.f, 0.f, 0.f, 0.f};

#define STAGE(buf, k0)                                                    \
  {                                                                       \
    _Pragma("unroll")                                                     \
    for (int i = 0; i < 4; ++i)                                           \
      load_lds16(gA[i] + (k0), &As[buf][(size_t)(tid + 256 * i) * 8]);    \
    _Pragma("unroll")                                                     \
    for (int i = 0; i < 2; ++i)                                           \
      load_lds16(gB[i] + (k0), &Bs[buf][(size_t)(tid + 256 * i) * 8]);    \
  }

  STAGE(0, 0)

  const int NK = IN_FEATURES / GBK;   // 16
  for (int kt = 0; kt < NK; ++kt) {
    __syncthreads();                  // drains vmcnt -> stage kt complete
    if (kt + 1 < NK) STAGE((kt + 1) & 1, (kt + 1) * GBK)
    const unsigned short* Ab = As[kt & 1];
    const unsigned short* Bb = Bs[kt & 1];
#pragma unroll
    for (int s = 0; s < 2; ++s) {
      bf16x8 a0 = *(const bf16x8*)(Ab + (((2 * w + 0) * 2 + s) * 64 + L) * 8);
      bf16x8 a1 = *(const bf16x8*)(Ab + (((2 * w + 1) * 2 + s) * 64 + L) * 8);
      bf16x8 b0 = *(const bf16x8*)(Bb + ((0 * 2 + s) * 64 + L) * 8);
      bf16x8 b1 = *(const bf16x8*)(Bb + ((1 * 2 + s) * 64 + L) * 8);
      bf16x8 b2 = *(const bf16x8*)(Bb + ((2 * 2 + s) * 64 + L) * 8);
      bf16x8 b3 = *(const bf16x8*)(Bb + ((3 * 2 + s) * 64 + L) * 8);
      acc[0][0] = __builtin_amdgcn_mfma_f32_16x16x32_bf16(a0, b0, acc[0][0], 0, 0, 0);
      acc[0][1] = __builtin_amdgcn_mfma_f32_16x16x32_bf16(a0, b1, acc[0][1], 0, 0, 0);
      acc[0][2] = __builtin_amdgcn_mfma_f32_16x16x32_bf16(a0, b2, acc[0][2], 0, 0, 0);
      acc[0][3] = __builtin_amdgcn_mfma_f32_16x16x32_bf16(a0, b3, acc[0][3], 0, 0, 0);
      acc[1][0] = __builtin_amdgcn_mfma_f32_16x16x32_bf16(a1, b0, acc[1][0], 0, 0, 0);
      acc[1][1] = __builtin_amdgcn_mfma_f32_16x16x32_bf16(a1, b1, acc[1][1], 0, 0, 0);
      acc[1][2] = __builtin_amdgcn_mfma_f32_16x16x32_bf16(a1, b2, acc[1][2], 0, 0, 0);
      acc[1][3] = __builtin_amdgcn_mfma_f32_16x16x32_bf16(a1, b3, acc[1][3], 0, 0, 0);
    }
  }

  // Epilogue: C/D layout col = L&15, row = (L>>4)*4 + reg (m89-verified)
  const int colL = L & 15;
  const int rowq = (L >> 4) * 4;
  float bv[4];
#pragma unroll
  for (int nb = 0; nb < 4; ++nb) bv[nb] = bias[n_tile + nb * 16 + colL];
#pragma unroll
  for (int bm = 0; bm < 2; ++bm) {
#pragma unroll
    for (int reg = 0; reg < 4; ++reg) {
      int row = m_tile + w * 32 + bm * 16 + rowq + reg;
#pragma unroll
      for (int nb = 0; nb < 4; ++nb) {
        out[(size_t)row * OUT_FEATURES + n_tile + nb * 16 + colL] =
            acc[bm][nb][reg] + bv[nb];
      }
    }
  }
}

extern "C" void kernel_launch(void* const* d_in, const int* in_sizes, int n_in,
                              void* d_out, int out_size, void* d_ws, size_t ws_size,
                              hipStream_t stream) {
  const float* x      = (const float*)d_in[0];
  const float* mean   = (const float*)d_in[1];
  const float* logstd = (const float*)d_in[2];
  const float* weight = (const float*)d_in[3];
  float* out = (float*)d_out;

  const int M = in_sizes[0] / IN_FEATURES;   // 4096

  // ws layout: xh bf16 [M*1024] | wh bf16 [ROWS] | bias f32 [1024]
  unsigned short* xh = (unsigned short*)d_ws;
  unsigned short* wh = (unsigned short*)((char*)d_ws + (size_t)M * IN_FEATURES * 2);
  float* biasf = (float*)((char*)wh + (size_t)ROWS * 2);

  const int n_chunks = M * IN_FEATURES / 8;
  prep_kernel<<<ROWS / 256, 256, 0, stream>>>(
      mean, logstd, weight, x, wh, biasf, xh, n_chunks);

  dim3 grid(OUT_FEATURES / GBN, M / GBM);
  gemm_mfma_kernel<<<grid, 256, 0, stream>>>(xh, wh, biasf, out);
}